// Round 22
// baseline (61.796 us; speedup 1.0000x reference)
//
#include <hip/hip_runtime.h>

typedef _Float16 f16;
typedef _Float16 f16x8 __attribute__((ext_vector_type(8)));
typedef _Float16 f16x4 __attribute__((ext_vector_type(4)));
typedef __fp16 fp16x2 __attribute__((ext_vector_type(2)));
typedef float f32x4 __attribute__((ext_vector_type(4)));

#define MFMA16(a, b, c) __builtin_amdgcn_mfma_f32_16x16x32_f16(a, b, c, 0, 0, 0)

constexpr int Bn = 8, Sn = 2048, En = 1024, Hn = 64;
constexpr int Mn = Bn * Sn;  // 16384
constexpr float QSCALE = 11.5415603f;  // 8 * log2(e): softmax in exp2 domain
constexpr float THR = 11.5f;           // defer-max threshold (log2 domain)

__device__ __forceinline__ void gload_lds16(const void* g, void* lds) {
    __builtin_amdgcn_global_load_lds(
        (const __attribute__((address_space(1))) void*)g,
        (__attribute__((address_space(3))) void*)lds, 16, 0, 0);
}
__device__ __forceinline__ void wait_vm5() {
    asm volatile("s_waitcnt vmcnt(5)" ::: "memory");
    __builtin_amdgcn_sched_barrier(0);
}
__device__ __forceinline__ void wait_vm0() {
    asm volatile("s_waitcnt vmcnt(0)" ::: "memory");
    __builtin_amdgcn_sched_barrier(0);
}
__device__ __forceinline__ void barrier_raw() {
    __builtin_amdgcn_s_barrier();
    __builtin_amdgcn_sched_barrier(0);
}
// packed f32x8 -> f16x8 via v_cvt_pkrtz_f16_f32 (2 floats/instr)
__device__ __forceinline__ f16x8 cvt8(float4 lo, float4 hi) {
    union { f16x8 v; fp16x2 h[4]; } u;
    u.h[0] = __builtin_amdgcn_cvt_pkrtz(lo.x, lo.y);
    u.h[1] = __builtin_amdgcn_cvt_pkrtz(lo.z, lo.w);
    u.h[2] = __builtin_amdgcn_cvt_pkrtz(hi.x, hi.y);
    u.h[3] = __builtin_amdgcn_cvt_pkrtz(hi.z, hi.w);
    return u.v;
}

// ---------------------------------------------------------------------------
// Fragment-linear layouts (one coalesced 1-KB wave-load per MFMA fragment):
//  Q/K: [b][t16 (s>>4)][kc (k>>5)][lane64][8]  where lane=(lhi,l15):
//       element (s&15, k&31 = lhi*8+j) at ((b*128+t16)*2+kc)*512 + lane*8 + j
//  V^T: [b][kt (key>>5)][ntv (h>>4)][lane64][8]:
//       element (h&15, kappa-slot lhi*8+j) at ((b*64+kt)*4+ntv)*512 + lane*8+j
// ---------------------------------------------------------------------------

// ---------------------------------------------------------------------------
// Kernel 0: one-time W fp32 -> fp16 repack, PRE-SWIZZLED:
// [kt=16][rr=192][c=64] f16; chunk stored at c ^ (rr & 7).
// ---------------------------------------------------------------------------
__global__ __launch_bounds__(256) void convw_kernel(
    const float* __restrict__ Wq, const float* __restrict__ Wk,
    const float* __restrict__ Wv, f16* __restrict__ Wc)
{
    const int h = blockIdx.x * 256 + threadIdx.x;
    const int kt = h / 1536;
    const int rem = h - kt * 1536;
    const int rr = rem >> 3;
    const int c = rem & 7;
    const int set = rr >> 6;
    const float* src = (set == 0 ? Wq : (set == 1 ? Wk : Wv))
                       + (size_t)(rr & 63) * En + kt * 64 + c * 8;
    float4 v0 = *reinterpret_cast<const float4*>(src);
    float4 v1 = *reinterpret_cast<const float4*>(src + 4);
    f16x8 o = cvt8(v0, v1);
    const int cs = c ^ (rr & 7);
    *reinterpret_cast<f16x8*>(Wc + (size_t)kt * 12288 + rr * 64 + cs * 8) = o;
}

// ---------------------------------------------------------------------------
// Kernel 1: QKV projection, N-SPLIT for 4 WGs/CU. Grid 1024 = (512 m-chunks
// x 2 n-halves), 256 thr (4 waves: rt=w&1 row-tile of 16, npair=w>>1 owns 3
// n-tiles of the half). Per k-step: 12-KB W half-slice + 8-KB x staged via
// coalesced global_load_lds (uniform 5 VMEM/wave), double-buffered 20-KB
// slab (40 KB total -> 4 WGs/CU = independently-phased barrier coverage).
// Same XOR swizzles / pkrtz / fragment-linear epilogue as round 18.
// ---------------------------------------------------------------------------
__global__ __launch_bounds__(256, 4) void proj_kernel(
    const float* __restrict__ x, const f16* __restrict__ Wc,
    const float* __restrict__ bq, const float* __restrict__ bk,
    const float* __restrict__ bv,
    f16* __restrict__ qws, f16* __restrict__ kws, f16* __restrict__ vtws)
{
    __shared__ __align__(16) char ldsb[2 * 20480];  // buf: 12288 W + 8192 x
    const int tid = threadIdx.x;
    const int w = tid >> 6, l = tid & 63;
    const int l15 = l & 15, lhi = l >> 4;
    const int rt = w & 1, npair = w >> 1;
    const int wg = blockIdx.x;
    const int mp = wg >> 1, nhalf = wg & 1;
    const int Mbase = mp * 32;

    f32x4 acc[3];
#pragma unroll
    for (int i = 0; i < 3; ++i) acc[i] = (f32x4){0.f, 0.f, 0.f, 0.f};

#define WSTAGE(buf, kb)                                                       \
    {                                                                         \
        const f16* wt_ = Wc + (size_t)(kb) * 12288 + nhalf * 6144;            \
        _Pragma("unroll")                                                     \
        for (int r_ = 0; r_ < 3; ++r_) {                                      \
            const int g_ = w * 3 + r_;                                        \
            gload_lds16(wt_ + g_ * 512 + l * 8,                               \
                        ldsb + (buf) * 20480 + g_ * 1024);                    \
        }                                                                     \
    }

#define XSTAGE(buf, kb)                                                       \
    {                                                                         \
        _Pragma("unroll")                                                     \
        for (int e_ = 0; e_ < 2; ++e_) {                                      \
            const int gx_ = w * 2 + e_;                                       \
            const int r_ = gx_ * 4 + (l >> 4);                                \
            const float* xs_ = x + (size_t)(Mbase + r_) * En + (kb) * 64      \
                               + (((l & 15) ^ (r_ & 7)) * 4);                 \
            gload_lds16(xs_, ldsb + (buf) * 20480 + 12288 + gx_ * 1024);      \
        }                                                                     \
    }

#define COMPUTE(buf)                                                          \
    {                                                                         \
        const int xrow_ = rt * 16 + l15;                                      \
        const char* xb_ = ldsb + (buf) * 20480 + 12288 + xrow_ * 256;         \
        f16x8 a_[2];                                                          \
        _Pragma("unroll")                                                     \
        for (int kc_ = 0; kc_ < 2; ++kc_) {                                   \
            const int c0_ = kc_ * 8 + lhi * 2;                                \
            float4 lo_ = *reinterpret_cast<const float4*>(                    \
                xb_ + ((c0_ ^ (l15 & 7)) * 16));                              \
            float4 hi_ = *reinterpret_cast<const float4*>(                    \
                xb_ + (((c0_ + 1) ^ (l15 & 7)) * 16));                        \
            a_[kc_] = cvt8(lo_, hi_);                                         \
        }                                                                     \
        _Pragma("unroll")                                                     \
        for (int i_ = 0; i_ < 3; ++i_) {                                      \
            const int row16_ = (npair * 3 + i_) * 16 + l15;                   \
            _Pragma("unroll")                                                 \
            for (int kc_ = 0; kc_ < 2; ++kc_) {                               \
                const int addr_ = (buf) * 20480 + row16_ * 128                \
                    + ((kc_ * 64 + lhi * 16) ^ ((l15 & 7) << 4));             \
                f16x8 b_ = *reinterpret_cast<const f16x8*>(ldsb + addr_);     \
                acc[i_] = MFMA16(a_[kc_], b_, acc[i_]);                       \
            }                                                                 \
        }                                                                     \
    }

    WSTAGE(0, 0);
    XSTAGE(0, 0);
#pragma unroll
    for (int i = 0; i < 16; ++i) {
        const int cur = i & 1;
        if (i < 15) {
            WSTAGE(cur ^ 1, i + 1);
            XSTAGE(cur ^ 1, i + 1);
            wait_vm5();   // step-i's 5 loads drained; step-(i+1)'s in flight
        } else {
            wait_vm0();
        }
        barrier_raw();    // all waves' stage of buf[cur] complete
        COMPUTE(cur);
        barrier_raw();    // all waves done reading buf[cur] before restage
    }
#undef WSTAGE
#undef XSTAGE
#undef COMPUTE

    const int batch = Mbase >> 11;
    const int r0 = Mbase + rt * 16 + lhi * 4;
#pragma unroll
    for (int i = 0; i < 3; ++i) {
        const int nt = nhalf * 6 + npair * 3 + i;
        const int set = nt >> 2;
        const int h = (nt & 3) * 16 + l15;
        const float bias = (set == 0 ? bq : (set == 1 ? bk : bv))[h];
        if (set < 2) {
            f16* dst = (set == 0) ? qws : kws;
            const float scale = (set == 0) ? QSCALE : 1.0f;
            const int kc = h >> 5;
            const int lhk = (h >> 3) & 3;
            const int j = h & 7;
#pragma unroll
            for (int r = 0; r < 4; ++r) {
                const int s = (r0 + r) & (Sn - 1);
                const int t16 = s >> 4;
                const int l15k = s & 15;
                dst[(size_t)((batch * 128 + t16) * 2 + kc) * 512
                    + (lhk * 16 + l15k) * 8 + j] =
                    (f16)((acc[i][r] + bias) * scale);
            }
        } else {
            const int s0v = r0 & (Sn - 1);
            const int kt = s0v >> 5;
            const int spl = ((s0v & 12) << 1) + ((s0v & 16) ? 4 : 0);  // kappa
            const int lhv = spl >> 3;
            const int j0 = spl & 7;                 // 0 or 4
            const int ntv = h >> 4;
            const int l15v = h & 15;
            f16x4 hv = {(f16)(acc[i][0] + bias), (f16)(acc[i][1] + bias),
                        (f16)(acc[i][2] + bias), (f16)(acc[i][3] + bias)};
            *reinterpret_cast<f16x4*>(
                &vtws[(size_t)((batch * 64 + kt) * 4 + ntv) * 512
                      + (lhv * 16 + l15v) * 8 + j0]) = hv;
        }
    }
}

// ---------------------------------------------------------------------------
// Kernel 2: causal flash attention (byte-identical to round 18/21):
// chunk = 8, 2304 units, grid 576, fragment-linear Q/K/V loads.
// ---------------------------------------------------------------------------
__global__ __launch_bounds__(256, 3) void attn_kernel(
    const f16* __restrict__ qws, const f16* __restrict__ kws,
    const f16* __restrict__ vtws, float* __restrict__ out,
    float* __restrict__ slots)
{
    const int tid = threadIdx.x;
    const int w = tid >> 6, l = tid & 63;
    const int l15 = l & 15, lhi = l >> 4;

    const int L = blockIdx.x * 4 + w;
    const int u = (int)(((unsigned)L * 997u) % 2304u);
    const int b = u / 288;
    const int t = u - b * 288;
    int k = 0;
#pragma unroll
    for (int gg = 1; gg < 8; ++gg)
        if (t >= 4 * gg * (gg + 1)) k = gg;
    const int rem = t - 4 * k * (k + 1);
    const int jq = rem / (k + 1);
    const int c = rem - jq * (k + 1);
    const int J = 8 * k + jq;

    const int qbase = J * 32;
    const int nkt = J + 1;
    const int ts = c * 8;
    const int te = (ts + 8 < nkt) ? ts + 8 : nkt;
    const bool hasDiag = (te == nkt);
    const int nfull = te - (hasDiag ? 1 : 0);

    f16x8 qf[2][2];
#pragma unroll
    for (int rs = 0; rs < 2; ++rs)
#pragma unroll
        for (int kc = 0; kc < 2; ++kc)
            qf[rs][kc] = *reinterpret_cast<const f16x8*>(
                &qws[(size_t)((b * 128 + J * 2 + rs) * 2 + kc) * 512 + l * 8]);

    f32x4 O[2][4];
#pragma unroll
    for (int rs = 0; rs < 2; ++rs)
#pragma unroll
        for (int nt = 0; nt < 4; ++nt) O[rs][nt] = (f32x4){0.f, 0.f, 0.f, 0.f};
    float m1[2] = {-1e30f, -1e30f}, l1[2] = {0.f, 0.f};

#define ATTN_ITER(KT, MASKED)                                                 \
    {                                                                         \
        f16x8 kf[2][2];                                                       \
        _Pragma("unroll") for (int nt = 0; nt < 2; ++nt)                      \
        _Pragma("unroll") for (int kc = 0; kc < 2; ++kc)                      \
            kf[nt][kc] = *reinterpret_cast<const f16x8*>(                     \
                &kws[(size_t)((b * 128 + (KT) * 2 + nt) * 2 + kc) * 512       \
                     + l * 8]);                                               \
        f32x4 Sv[2][2];                                                       \
        _Pragma("unroll") for (int rs = 0; rs < 2; ++rs)                      \
        _Pragma("unroll") for (int nt = 0; nt < 2; ++nt) {                    \
            f32x4 sa = (f32x4){0.f, 0.f, 0.f, 0.f};                           \
            sa = MFMA16(kf[nt][0], qf[rs][0], sa);                            \
            sa = MFMA16(kf[nt][1], qf[rs][1], sa);                            \
            Sv[rs][nt] = sa;                                                  \
        }                                                                     \
        float tv[2][2][4];                                                    \
        float mx[2];                                                          \
        _Pragma("unroll") for (int rs = 0; rs < 2; ++rs) {                    \
            _Pragma("unroll") for (int nt = 0; nt < 2; ++nt)                  \
            _Pragma("unroll") for (int r = 0; r < 4; ++r) {                   \
                float v = Sv[rs][nt][r];                                      \
                if (MASKED) {                                                 \
                    const int key_ = nt * 16 + lhi * 4 + r;                   \
                    const int qq_ = rs * 16 + l15;                            \
                    v = (key_ <= qq_) ? v : -1e30f;                           \
                }                                                             \
                tv[rs][nt][r] = v;                                            \
            }                                                                 \
            float a0 = fmaxf(fmaxf(tv[rs][0][0], tv[rs][0][1]),               \
                             fmaxf(tv[rs][0][2], tv[rs][0][3]));              \
            float a1 = fmaxf(fmaxf(tv[rs][1][0], tv[rs][1][1]),               \
                             fmaxf(tv[rs][1][2], tv[rs][1][3]));              \
            float m_ = fmaxf(a0, a1);                                         \
            m_ = fmaxf(m_, __shfl_xor(m_, 16));                               \
            m_ = fmaxf(m_, __shfl_xor(m_, 32));                               \
            mx[rs] = m_;                                                      \
        }                                                                     \
        const int need = (mx[0] > m1[0] + THR) || (mx[1] > m1[1] + THR);      \
        if (__any(need)) {                                                    \
            _Pragma("unroll") for (int rs = 0; rs < 2; ++rs) {                \
                const float mn = fmaxf(m1[rs], mx[rs]);                       \
                const float al = exp2f(m1[rs] - mn);                          \
                l1[rs] *= al;                                                 \
                _Pragma("unroll") for (int nt = 0; nt < 4; ++nt)              \
                _Pragma("unroll") for (int r = 0; r < 4; ++r)                 \
                    O[rs][nt][r] *= al;                                       \
                m1[rs] = mn;                                                  \
            }                                                                 \
        }                                                                     \
        f16x8 pa[2];                                                          \
        _Pragma("unroll") for (int rs = 0; rs < 2; ++rs) {                    \
            float p_[8];                                                      \
            float s_ = 0.f;                                                   \
            _Pragma("unroll") for (int nt = 0; nt < 2; ++nt)                  \
            _Pragma("unroll") for (int r = 0; r < 4; ++r) {                   \
                const float e_ = exp2f(tv[rs][nt][r] - m1[rs]);               \
                p_[nt * 4 + r] = e_;                                          \
                s_ += e_;                                                     \
            }                                                                 \
            s_ += __shfl_xor(s_, 16);                                         \
            s_ += __shfl_xor(s_, 32);                                         \
            l1[rs] += s_;                                                     \
            pa[rs] = (f16x8){(f16)p_[0], (f16)p_[1], (f16)p_[2], (f16)p_[3],  \
                             (f16)p_[4], (f16)p_[5], (f16)p_[6], (f16)p_[7]}; \
        }                                                                     \
        _Pragma("unroll") for (int nt = 0; nt < 4; ++nt) {                    \
            f16x8 vf = *reinterpret_cast<const f16x8*>(                       \
                &vtws[(size_t)((b * 64 + (KT)) * 4 + nt) * 512 + l * 8]);     \
            O[0][nt] = MFMA16(vf, pa[0], O[0][nt]);                           \
            O[1][nt] = MFMA16(vf, pa[1], O[1][nt]);                           \
        }                                                                     \
    }

    for (int kt = ts; kt < nfull; ++kt) ATTN_ITER(kt, false);
    if (hasDiag) ATTN_ITER(J, true);
#undef ATTN_ITER

    if (J < 8) {
#pragma unroll
        for (int rs = 0; rs < 2; ++rs) {
            const float inv = 1.0f / l1[rs];
            const size_t ro = ((size_t)b * Sn + qbase + rs * 16 + l15) * Hn;
#pragma unroll
            for (int nt = 0; nt < 4; ++nt) {
                float4 o = {O[rs][nt][0] * inv, O[rs][nt][1] * inv,
                            O[rs][nt][2] * inv, O[rs][nt][3] * inv};
                *reinterpret_cast<float4*>(&out[ro + nt * 16 + lhi * 4]) = o;
            }
        }
    } else {
        float* sl = slots + (size_t)(b * 280 + 4 * k * (k + 1) - 8
                                     + jq * (k + 1) + c) * 1088;
        f16* so = reinterpret_cast<f16*>(sl + 64);
#pragma unroll
        for (int rs = 0; rs < 2; ++rs) {
            const int row = rs * 16 + l15;
            const float inv = 1.0f / l1[rs];
            if (lhi == 0) { sl[row] = m1[rs]; sl[32 + row] = l1[rs]; }
#pragma unroll
            for (int nt = 0; nt < 4; ++nt) {
                f16x4 hv = {(f16)(O[rs][nt][0] * inv), (f16)(O[rs][nt][1] * inv),
                            (f16)(O[rs][nt][2] * inv), (f16)(O[rs][nt][3] * inv)};
                *reinterpret_cast<f16x4*>(
                    &so[row * 64 + nt * 16 + lhi * 4]) = hv;
            }
        }
    }
}

// ---------------------------------------------------------------------------
// Kernel 3: merge chunk partials for q-blocks J>=8. grid = 8 x 56 = 448.
// ---------------------------------------------------------------------------
__global__ __launch_bounds__(256) void comb_kernel(
    const float* __restrict__ slots, float* __restrict__ out)
{
    const int id = blockIdx.x;
    const int b = id / 56, jj = id - b * 56;
    const int J = 8 + jj;
    const int k = J >> 3;
    const int nch = k + 1;
    const float* base = slots + (size_t)(b * 280 + 4 * k * (k + 1) - 8
                                         + (J - 8 * k) * (k + 1)) * 1088;
    const int tid = threadIdx.x;
    const int row = tid >> 3;
    const int h0 = (tid & 7) * 8;

    float mg = -1e30f;
    for (int cc = 0; cc < nch; ++cc)
        mg = fmaxf(mg, base[cc * 1088 + row]);
    float den = 0.f;
    float num[8] = {0.f, 0.f, 0.f, 0.f, 0.f, 0.f, 0.f, 0.f};
    for (int cc = 0; cc < nch; ++cc) {
        const float* sl = base + cc * 1088;
        const float wgt = sl[32 + row] * exp2f(sl[row] - mg);
        den += wgt;
        const f16* so = reinterpret_cast<const f16*>(sl + 64);
        f16x8 ov = *reinterpret_cast<const f16x8*>(&so[row * 64 + h0]);
#pragma unroll
        for (int i = 0; i < 8; ++i) num[i] += (float)ov[i] * wgt;
    }
    const float inv = 1.0f / den;
    const size_t ro = ((size_t)b * Sn + J * 32 + row) * Hn + h0;
    float4 o0 = {num[0] * inv, num[1] * inv, num[2] * inv, num[3] * inv};
    float4 o1 = {num[4] * inv, num[5] * inv, num[6] * inv, num[7] * inv};
    *reinterpret_cast<float4*>(&out[ro]) = o0;
    *reinterpret_cast<float4*>(&out[ro + 4]) = o1;
}

// ---------------------------------------------------------------------------
extern "C" void kernel_launch(void* const* d_in, const int* in_sizes, int n_in,
                              void* d_out, int out_size, void* d_ws, size_t ws_size,
                              hipStream_t stream) {
    const float* x  = (const float*)d_in[0];
    const float* Wk = (const float*)d_in[1];
    const float* bk = (const float*)d_in[2];
    const float* Wq = (const float*)d_in[3];
    const float* bq = (const float*)d_in[4];
    const float* Wv = (const float*)d_in[5];
    const float* bv = (const float*)d_in[6];

    f16* qws  = (f16*)d_ws;                    // 2 MB (fragment-linear, xQSCALE)
    f16* kws  = qws + (size_t)Mn * Hn;         // 2 MB (fragment-linear)
    f16* vtws = kws + (size_t)Mn * Hn;         // 2 MB (fragment-linear + kappa)
    f16* Wc   = vtws + (size_t)Mn * Hn;        // 384 KB (kt-sliced, swizzled)
    float* slots = (float*)(Wc + 196608);      // 2240 * 1088 f32 (~9.75 MB)

    convw_kernel<<<96, 256, 0, stream>>>(Wq, Wk, Wv, Wc);
    proj_kernel<<<1024, 256, 0, stream>>>(x, Wc, bq, bk, bv, qws, kws, vtws);
    attn_kernel<<<576, 256, 0, stream>>>(qws, kws, vtws, (float*)d_out, slots);
    comb_kernel<<<448, 256, 0, stream>>>(slots, (float*)d_out);
}

// Round 23
// 53.281 us; speedup vs baseline: 1.1598x; 1.1598x over previous
//
#include <hip/hip_runtime.h>

typedef _Float16 f16;
typedef _Float16 f16x8 __attribute__((ext_vector_type(8)));
typedef _Float16 f16x4 __attribute__((ext_vector_type(4)));
typedef __fp16 fp16x2 __attribute__((ext_vector_type(2)));
typedef float f32x4 __attribute__((ext_vector_type(4)));

#define MFMA16(a, b, c) __builtin_amdgcn_mfma_f32_16x16x32_f16(a, b, c, 0, 0, 0)

constexpr int Bn = 8, Sn = 2048, En = 1024, Hn = 64;
constexpr int Mn = Bn * Sn;  // 16384
constexpr float QSCALE = 11.5415603f;  // 8 * log2(e): softmax in exp2 domain
constexpr float THR = 11.5f;           // defer-max threshold (log2 domain)

__device__ __forceinline__ void gload_lds16(const void* g, void* lds) {
    __builtin_amdgcn_global_load_lds(
        (const __attribute__((address_space(1))) void*)g,
        (__attribute__((address_space(3))) void*)lds, 16, 0, 0);
}
__device__ __forceinline__ void wait_vm4() {
    asm volatile("s_waitcnt vmcnt(4)" ::: "memory");
    __builtin_amdgcn_sched_barrier(0);
}
__device__ __forceinline__ void wait_vm0() {
    asm volatile("s_waitcnt vmcnt(0)" ::: "memory");
    __builtin_amdgcn_sched_barrier(0);
}
__device__ __forceinline__ void barrier_raw() {
    __builtin_amdgcn_s_barrier();
    __builtin_amdgcn_sched_barrier(0);
}
// packed f32x8 -> f16x8 via v_cvt_pkrtz_f16_f32 (2 floats/instr)
__device__ __forceinline__ f16x8 cvt8(float4 lo, float4 hi) {
    union { f16x8 v; fp16x2 h[4]; } u;
    u.h[0] = __builtin_amdgcn_cvt_pkrtz(lo.x, lo.y);
    u.h[1] = __builtin_amdgcn_cvt_pkrtz(lo.z, lo.w);
    u.h[2] = __builtin_amdgcn_cvt_pkrtz(hi.x, hi.y);
    u.h[3] = __builtin_amdgcn_cvt_pkrtz(hi.z, hi.w);
    return u.v;
}

// ---------------------------------------------------------------------------
// Fragment-linear layouts (one coalesced 1-KB wave-load per MFMA fragment):
//  Q/K: [b][t16 (s>>4)][kc (k>>5)][lane64][8]  where lane=(lhi,l15):
//       element (s&15, k&31 = lhi*8+j) at ((b*128+t16)*2+kc)*512 + lane*8 + j
//  V^T: [b][kt (key>>5)][ntv (h>>4)][lane64][8]:
//       element (h&15, kappa-slot lhi*8+j) at ((b*64+kt)*4+ntv)*512 + lane*8+j
// ---------------------------------------------------------------------------

// ---------------------------------------------------------------------------
// Kernel 0: one-time W fp32 -> fp16 repack, PRE-SWIZZLED:
// [kt=16][rr=192][c=64] f16; chunk stored at c ^ (rr & 7).
// ---------------------------------------------------------------------------
__global__ __launch_bounds__(256) void convw_kernel(
    const float* __restrict__ Wq, const float* __restrict__ Wk,
    const float* __restrict__ Wv, f16* __restrict__ Wc)
{
    const int h = blockIdx.x * 256 + threadIdx.x;
    const int kt = h / 1536;
    const int rem = h - kt * 1536;
    const int rr = rem >> 3;
    const int c = rem & 7;
    const int set = rr >> 6;
    const float* src = (set == 0 ? Wq : (set == 1 ? Wk : Wv))
                       + (size_t)(rr & 63) * En + kt * 64 + c * 8;
    float4 v0 = *reinterpret_cast<const float4*>(src);
    float4 v1 = *reinterpret_cast<const float4*>(src + 4);
    f16x8 o = cvt8(v0, v1);
    const int cs = c ^ (rr & 7);
    *reinterpret_cast<f16x8*>(Wc + (size_t)kt * 12288 + rr * 64 + cs * 8) = o;
}

// ---------------------------------------------------------------------------
// Kernel 1: QKV projection — round-12 structure + pkrtz: BM=32, grid 512
// (2 WGs/CU), 512 thr; W 24 KB + x 8 KB staged per k-step via coalesced
// global_load_lds, double-buffered 32-KB slab, XOR pre-swizzled sources,
// counted vmcnt(4). Fragment-linear epilogue.
// ---------------------------------------------------------------------------
__global__ __launch_bounds__(512) void proj_kernel(
    const float* __restrict__ x, const f16* __restrict__ Wc,
    const float* __restrict__ bq, const float* __restrict__ bk,
    const float* __restrict__ bv,
    f16* __restrict__ qws, f16* __restrict__ kws, f16* __restrict__ vtws)
{
    __shared__ __align__(16) char ldsb[2 * 32768];  // buf: 24576 W + 8192 x
    const int tid = threadIdx.x;
    const int w = tid >> 6, l = tid & 63;
    const int l15 = l & 15, lhi = l >> 4;
    const int rt = w & 1, nh = w >> 1;
    const int Mbase = blockIdx.x * 32;

    f32x4 acc[3];
#pragma unroll
    for (int i = 0; i < 3; ++i) acc[i] = (f32x4){0.f, 0.f, 0.f, 0.f};

    const int xr_s = w * 4 + (l >> 4);             // staged row 0..31
    const int xc_s = (l & 15) ^ (xr_s & 7);        // pre-swizzled src chunk

#define WSTAGE(buf, kb)                                                       \
    {                                                                         \
        const f16* wt_ = Wc + (size_t)(kb) * 12288;                           \
        _Pragma("unroll")                                                     \
        for (int r_ = 0; r_ < 3; ++r_)                                        \
            gload_lds16(wt_ + r_ * 4096 + w * 512 + l * 8,                    \
                        ldsb + (buf) * 32768 + r_ * 8192 + w * 1024);         \
    }

#define XSTAGE(buf, kb)                                                       \
    {                                                                         \
        const float* xs_ = x + (size_t)(Mbase + xr_s) * En + (kb) * 64        \
                           + xc_s * 4;                                        \
        gload_lds16(xs_, ldsb + (buf) * 32768 + 24576 + w * 1024);            \
    }

#define COMPUTE(buf)                                                          \
    {                                                                         \
        const int xrow_ = rt * 16 + l15;                                      \
        const char* xb_ = ldsb + (buf) * 32768 + 24576 + xrow_ * 256;         \
        f16x8 a_[2];                                                          \
        _Pragma("unroll")                                                     \
        for (int kc_ = 0; kc_ < 2; ++kc_) {                                   \
            const int c0_ = kc_ * 8 + lhi * 2;                                \
            float4 lo_ = *reinterpret_cast<const float4*>(                    \
                xb_ + ((c0_ ^ (l15 & 7)) * 16));                              \
            float4 hi_ = *reinterpret_cast<const float4*>(                    \
                xb_ + (((c0_ + 1) ^ (l15 & 7)) * 16));                        \
            a_[kc_] = cvt8(lo_, hi_);                                         \
        }                                                                     \
        _Pragma("unroll")                                                     \
        for (int i_ = 0; i_ < 3; ++i_) {                                      \
            const int row16_ = (nh * 3 + i_) * 16 + l15;                      \
            _Pragma("unroll")                                                 \
            for (int kc_ = 0; kc_ < 2; ++kc_) {                               \
                const int addr_ = (buf) * 32768 + row16_ * 128                \
                    + ((kc_ * 64 + lhi * 16) ^ ((l15 & 7) << 4));             \
                f16x8 b_ = *reinterpret_cast<const f16x8*>(ldsb + addr_);     \
                acc[i_] = MFMA16(a_[kc_], b_, acc[i_]);                       \
            }                                                                 \
        }                                                                     \
    }

    WSTAGE(0, 0);
    XSTAGE(0, 0);
#pragma unroll
    for (int i = 0; i < 16; ++i) {
        const int cur = i & 1;
        if (i < 15) {
            WSTAGE(cur ^ 1, i + 1);
            XSTAGE(cur ^ 1, i + 1);
            wait_vm4();   // step-i's 4 loads drained; step-(i+1)'s in flight
        } else {
            wait_vm0();
        }
        barrier_raw();    // all waves' stage of buf[cur] complete
        COMPUTE(cur);
        barrier_raw();    // all waves done reading buf[cur] before restage
    }
#undef WSTAGE
#undef XSTAGE
#undef COMPUTE

    const int batch = Mbase >> 11;
    const int r0 = Mbase + rt * 16 + lhi * 4;
#pragma unroll
    for (int i = 0; i < 3; ++i) {
        const int nt = nh * 3 + i;
        const int set = nt >> 2;
        const int h = (nt & 3) * 16 + l15;
        const float bias = (set == 0 ? bq : (set == 1 ? bk : bv))[h];
        if (set < 2) {
            f16* dst = (set == 0) ? qws : kws;
            const float scale = (set == 0) ? QSCALE : 1.0f;
            const int kc = h >> 5;
            const int lhk = (h >> 3) & 3;
            const int j = h & 7;
#pragma unroll
            for (int r = 0; r < 4; ++r) {
                const int s = (r0 + r) & (Sn - 1);
                const int t16 = s >> 4;
                const int l15k = s & 15;
                dst[(size_t)((batch * 128 + t16) * 2 + kc) * 512
                    + (lhk * 16 + l15k) * 8 + j] =
                    (f16)((acc[i][r] + bias) * scale);
            }
        } else {
            const int s0v = r0 & (Sn - 1);
            const int kt = s0v >> 5;
            const int spl = ((s0v & 12) << 1) + ((s0v & 16) ? 4 : 0);  // kappa
            const int lhv = spl >> 3;
            const int j0 = spl & 7;                 // 0 or 4
            const int ntv = h >> 4;
            const int l15v = h & 15;
            f16x4 hv = {(f16)(acc[i][0] + bias), (f16)(acc[i][1] + bias),
                        (f16)(acc[i][2] + bias), (f16)(acc[i][3] + bias)};
            *reinterpret_cast<f16x4*>(
                &vtws[(size_t)((batch * 64 + kt) * 4 + ntv) * 512
                      + (lhv * 16 + l15v) * 8 + j0]) = hv;
        }
    }
}

// ---------------------------------------------------------------------------
// Kernel 2: causal flash attention — round-12 structure (chunk = 8, 2304
// units, grid 576) with FRAGMENT-LINEAR Q/K/V loads: one coalesced 1-KB
// wave-load per MFMA fragment.
// ---------------------------------------------------------------------------
__global__ __launch_bounds__(256, 3) void attn_kernel(
    const f16* __restrict__ qws, const f16* __restrict__ kws,
    const f16* __restrict__ vtws, float* __restrict__ out,
    float* __restrict__ slots)
{
    const int tid = threadIdx.x;
    const int w = tid >> 6, l = tid & 63;
    const int l15 = l & 15, lhi = l >> 4;

    const int L = blockIdx.x * 4 + w;
    const int u = (int)(((unsigned)L * 997u) % 2304u);
    const int b = u / 288;
    const int t = u - b * 288;
    int k = 0;
#pragma unroll
    for (int gg = 1; gg < 8; ++gg)
        if (t >= 4 * gg * (gg + 1)) k = gg;
    const int rem = t - 4 * k * (k + 1);
    const int jq = rem / (k + 1);
    const int c = rem - jq * (k + 1);
    const int J = 8 * k + jq;

    const int qbase = J * 32;
    const int nkt = J + 1;
    const int ts = c * 8;
    const int te = (ts + 8 < nkt) ? ts + 8 : nkt;
    const bool hasDiag = (te == nkt);
    const int nfull = te - (hasDiag ? 1 : 0);

    f16x8 qf[2][2];
#pragma unroll
    for (int rs = 0; rs < 2; ++rs)
#pragma unroll
        for (int kc = 0; kc < 2; ++kc)
            qf[rs][kc] = *reinterpret_cast<const f16x8*>(
                &qws[(size_t)((b * 128 + J * 2 + rs) * 2 + kc) * 512 + l * 8]);

    f32x4 O[2][4];
#pragma unroll
    for (int rs = 0; rs < 2; ++rs)
#pragma unroll
        for (int nt = 0; nt < 4; ++nt) O[rs][nt] = (f32x4){0.f, 0.f, 0.f, 0.f};
    float m1[2] = {-1e30f, -1e30f}, l1[2] = {0.f, 0.f};

#define ATTN_ITER(KT, MASKED)                                                 \
    {                                                                         \
        f16x8 kf[2][2];                                                       \
        _Pragma("unroll") for (int nt = 0; nt < 2; ++nt)                      \
        _Pragma("unroll") for (int kc = 0; kc < 2; ++kc)                      \
            kf[nt][kc] = *reinterpret_cast<const f16x8*>(                     \
                &kws[(size_t)((b * 128 + (KT) * 2 + nt) * 2 + kc) * 512       \
                     + l * 8]);                                               \
        f32x4 Sv[2][2];                                                       \
        _Pragma("unroll") for (int rs = 0; rs < 2; ++rs)                      \
        _Pragma("unroll") for (int nt = 0; nt < 2; ++nt) {                    \
            f32x4 sa = (f32x4){0.f, 0.f, 0.f, 0.f};                           \
            sa = MFMA16(kf[nt][0], qf[rs][0], sa);                            \
            sa = MFMA16(kf[nt][1], qf[rs][1], sa);                            \
            Sv[rs][nt] = sa;                                                  \
        }                                                                     \
        float tv[2][2][4];                                                    \
        float mx[2];                                                          \
        _Pragma("unroll") for (int rs = 0; rs < 2; ++rs) {                    \
            _Pragma("unroll") for (int nt = 0; nt < 2; ++nt)                  \
            _Pragma("unroll") for (int r = 0; r < 4; ++r) {                   \
                float v = Sv[rs][nt][r];                                      \
                if (MASKED) {                                                 \
                    const int key_ = nt * 16 + lhi * 4 + r;                   \
                    const int qq_ = rs * 16 + l15;                            \
                    v = (key_ <= qq_) ? v : -1e30f;                           \
                }                                                             \
                tv[rs][nt][r] = v;                                            \
            }                                                                 \
            float a0 = fmaxf(fmaxf(tv[rs][0][0], tv[rs][0][1]),               \
                             fmaxf(tv[rs][0][2], tv[rs][0][3]));              \
            float a1 = fmaxf(fmaxf(tv[rs][1][0], tv[rs][1][1]),               \
                             fmaxf(tv[rs][1][2], tv[rs][1][3]));              \
            float m_ = fmaxf(a0, a1);                                         \
            m_ = fmaxf(m_, __shfl_xor(m_, 16));                               \
            m_ = fmaxf(m_, __shfl_xor(m_, 32));                               \
            mx[rs] = m_;                                                      \
        }                                                                     \
        const int need = (mx[0] > m1[0] + THR) || (mx[1] > m1[1] + THR);      \
        if (__any(need)) {                                                    \
            _Pragma("unroll") for (int rs = 0; rs < 2; ++rs) {                \
                const float mn = fmaxf(m1[rs], mx[rs]);                       \
                const float al = exp2f(m1[rs] - mn);                          \
                l1[rs] *= al;                                                 \
                _Pragma("unroll") for (int nt = 0; nt < 4; ++nt)              \
                _Pragma("unroll") for (int r = 0; r < 4; ++r)                 \
                    O[rs][nt][r] *= al;                                       \
                m1[rs] = mn;                                                  \
            }                                                                 \
        }                                                                     \
        f16x8 pa[2];                                                          \
        _Pragma("unroll") for (int rs = 0; rs < 2; ++rs) {                    \
            float p_[8];                                                      \
            float s_ = 0.f;                                                   \
            _Pragma("unroll") for (int nt = 0; nt < 2; ++nt)                  \
            _Pragma("unroll") for (int r = 0; r < 4; ++r) {                   \
                const float e_ = exp2f(tv[rs][nt][r] - m1[rs]);               \
                p_[nt * 4 + r] = e_;                                          \
                s_ += e_;                                                     \
            }                                                                 \
            s_ += __shfl_xor(s_, 16);                                         \
            s_ += __shfl_xor(s_, 32);                                         \
            l1[rs] += s_;                                                     \
            pa[rs] = (f16x8){(f16)p_[0], (f16)p_[1], (f16)p_[2], (f16)p_[3],  \
                             (f16)p_[4], (f16)p_[5], (f16)p_[6], (f16)p_[7]}; \
        }                                                                     \
        _Pragma("unroll") for (int nt = 0; nt < 4; ++nt) {                    \
            f16x8 vf = *reinterpret_cast<const f16x8*>(                       \
                &vtws[(size_t)((b * 64 + (KT)) * 4 + nt) * 512 + l * 8]);     \
            O[0][nt] = MFMA16(vf, pa[0], O[0][nt]);                           \
            O[1][nt] = MFMA16(vf, pa[1], O[1][nt]);                           \
        }                                                                     \
    }

    for (int kt = ts; kt < nfull; ++kt) ATTN_ITER(kt, false);
    if (hasDiag) ATTN_ITER(J, true);
#undef ATTN_ITER

    if (J < 8) {
#pragma unroll
        for (int rs = 0; rs < 2; ++rs) {
            const float inv = 1.0f / l1[rs];
            const size_t ro = ((size_t)b * Sn + qbase + rs * 16 + l15) * Hn;
#pragma unroll
            for (int nt = 0; nt < 4; ++nt) {
                float4 o = {O[rs][nt][0] * inv, O[rs][nt][1] * inv,
                            O[rs][nt][2] * inv, O[rs][nt][3] * inv};
                *reinterpret_cast<float4*>(&out[ro + nt * 16 + lhi * 4]) = o;
            }
        }
    } else {
        float* sl = slots + (size_t)(b * 280 + 4 * k * (k + 1) - 8
                                     + jq * (k + 1) + c) * 1088;
        f16* so = reinterpret_cast<f16*>(sl + 64);
#pragma unroll
        for (int rs = 0; rs < 2; ++rs) {
            const int row = rs * 16 + l15;
            const float inv = 1.0f / l1[rs];
            if (lhi == 0) { sl[row] = m1[rs]; sl[32 + row] = l1[rs]; }
#pragma unroll
            for (int nt = 0; nt < 4; ++nt) {
                f16x4 hv = {(f16)(O[rs][nt][0] * inv), (f16)(O[rs][nt][1] * inv),
                            (f16)(O[rs][nt][2] * inv), (f16)(O[rs][nt][3] * inv)};
                *reinterpret_cast<f16x4*>(
                    &so[row * 64 + nt * 16 + lhi * 4]) = hv;
            }
        }
    }
}

// ---------------------------------------------------------------------------
// Kernel 3: merge chunk partials for q-blocks J>=8. grid = 8 x 56 = 448.
// ---------------------------------------------------------------------------
__global__ __launch_bounds__(256) void comb_kernel(
    const float* __restrict__ slots, float* __restrict__ out)
{
    const int id = blockIdx.x;
    const int b = id / 56, jj = id - b * 56;
    const int J = 8 + jj;
    const int k = J >> 3;
    const int nch = k + 1;
    const float* base = slots + (size_t)(b * 280 + 4 * k * (k + 1) - 8
                                         + (J - 8 * k) * (k + 1)) * 1088;
    const int tid = threadIdx.x;
    const int row = tid >> 3;
    const int h0 = (tid & 7) * 8;

    float mg = -1e30f;
    for (int cc = 0; cc < nch; ++cc)
        mg = fmaxf(mg, base[cc * 1088 + row]);
    float den = 0.f;
    float num[8] = {0.f, 0.f, 0.f, 0.f, 0.f, 0.f, 0.f, 0.f};
    for (int cc = 0; cc < nch; ++cc) {
        const float* sl = base + cc * 1088;
        const float wgt = sl[32 + row] * exp2f(sl[row] - mg);
        den += wgt;
        const f16* so = reinterpret_cast<const f16*>(sl + 64);
        f16x8 ov = *reinterpret_cast<const f16x8*>(&so[row * 64 + h0]);
#pragma unroll
        for (int i = 0; i < 8; ++i) num[i] += (float)ov[i] * wgt;
    }
    const float inv = 1.0f / den;
    const size_t ro = ((size_t)b * Sn + J * 32 + row) * Hn + h0;
    float4 o0 = {num[0] * inv, num[1] * inv, num[2] * inv, num[3] * inv};
    float4 o1 = {num[4] * inv, num[5] * inv, num[6] * inv, num[7] * inv};
    *reinterpret_cast<float4*>(&out[ro]) = o0;
    *reinterpret_cast<float4*>(&out[ro + 4]) = o1;
}

// ---------------------------------------------------------------------------
extern "C" void kernel_launch(void* const* d_in, const int* in_sizes, int n_in,
                              void* d_out, int out_size, void* d_ws, size_t ws_size,
                              hipStream_t stream) {
    const float* x  = (const float*)d_in[0];
    const float* Wk = (const float*)d_in[1];
    const float* bk = (const float*)d_in[2];
    const float* Wq = (const float*)d_in[3];
    const float* bq = (const float*)d_in[4];
    const float* Wv = (const float*)d_in[5];
    const float* bv = (const float*)d_in[6];

    f16* qws  = (f16*)d_ws;                    // 2 MB (fragment-linear, xQSCALE)
    f16* kws  = qws + (size_t)Mn * Hn;         // 2 MB (fragment-linear)
    f16* vtws = kws + (size_t)Mn * Hn;         // 2 MB (fragment-linear + kappa)
    f16* Wc   = vtws + (size_t)Mn * Hn;        // 384 KB (kt-sliced, swizzled)
    float* slots = (float*)(Wc + 196608);      // 2240 * 1088 f32 (~9.75 MB)

    convw_kernel<<<96, 256, 0, stream>>>(Wq, Wk, Wv, Wc);
    proj_kernel<<<512, 512, 0, stream>>>(x, Wc, bq, bk, bv, qws, kws, vtws);
    attn_kernel<<<576, 256, 0, stream>>>(qws, kws, vtws, (float*)d_out, slots);
    comb_kernel<<<448, 256, 0, stream>>>(slots, (float*)d_out);
}